// Round 2
// baseline (334.085 us; speedup 1.0000x reference)
//
#include <hip/hip_runtime.h>
#include <hip/hip_bf16.h>

// Attention: B=2, S=2048, D=2048, NH=32, NKV=8, HD=64, causal, RoPE, GQA.
// Inputs fp32, OUTPUT fp32. Internal bf16 MFMA, fp32 accumulate.
//
// ws layout (63 MB, bf16 elems):
//   xb/Obuf :  8,388,608 (4096x2048) — xb dead after QKV GEMM, reused as Obuf
//   qkv     : 12,582,912 (4096x3072)
//   woT     :  4,194,304 (2048x2048)
//   wqkvT/Vt:  6,291,456 — wqkvT dead after QKV GEMM, reused as Vt[b*8+kh][64][2048]

#define S_LEN 2048
#define BATCH 2
#define D_MODEL 2048
#define NH 32
#define NKV 8
#define HD 64
#define KV_D (NKV * HD)            // 512
#define QKV_N (D_MODEL + 2 * KV_D) // 3072

typedef __attribute__((ext_vector_type(8))) short short8;
typedef __attribute__((ext_vector_type(4))) float float4v;
typedef __attribute__((ext_vector_type(16))) float f32x16;
typedef __attribute__((ext_vector_type(2))) unsigned uint2v;

typedef __attribute__((address_space(1))) const unsigned int gu32;
typedef __attribute__((address_space(3))) unsigned int lu32;

// Q is pre-scaled by 0.125*log2(e) in rope2; scores then feed v_exp_f32 (2^x) raw.
#if __has_builtin(__builtin_amdgcn_exp2f)
#define PEXP(x) __builtin_amdgcn_exp2f(x)
#else
#define PEXP(x) __expf((x) * 0.69314718f)
#endif
#define QSCALE 0.18033688f  // 0.125 * log2(e)

__device__ __forceinline__ float bf2f(unsigned short u) {
    unsigned x = ((unsigned)u) << 16;
    return __builtin_bit_cast(float, x);
}
__device__ __forceinline__ unsigned short f2bf(float f) {
    unsigned u = __builtin_bit_cast(unsigned, f);
    unsigned r = (u + 0x7fffu + ((u >> 16) & 1u)) >> 16;
    return (unsigned short)r;
}

// packed f32x2 -> bf16x2 (RNE), single instruction
__device__ __forceinline__ unsigned cvt_pk_bf16(float a, float b) {
    unsigned r;
    asm("v_cvt_pk_bf16_f32 %0, %1, %2" : "=v"(r) : "v"(a), "v"(b));
    return r;
}

// permlane32_swap(a, b) -> (x, y): x = [lo: a(self) | hi: b(partner)],
// y = [lo: a(partner) | hi: b(self)]  (m214-verified operand order)
__device__ __forceinline__ void pl32swap(unsigned a, unsigned b,
                                         unsigned& x, unsigned& y) {
#if __has_builtin(__builtin_amdgcn_permlane32_swap)
    uint2v r = __builtin_amdgcn_permlane32_swap(a, b, false, false);
    x = r[0];
    y = r[1];
#else
    unsigned pa = (unsigned)__shfl_xor((int)a, 32);
    unsigned pb = (unsigned)__shfl_xor((int)b, 32);
    bool lo = (threadIdx.x & 63) < 32;
    x = lo ? a : pb;
    y = lo ? pa : b;
#endif
}

// fp32 -> bf16 elementwise cast, 4 elems/thread.
__global__ void cast_f32_bf16(const float* __restrict__ in,
                              unsigned short* __restrict__ out, long n) {
    long i = ((long)blockIdx.x * 256 + threadIdx.x) * 4;
    if (i + 3 >= n) return;
    const float4v v = *(const float4v*)&in[i];
    unsigned short o[4];
    o[0] = f2bf(v[0]); o[1] = f2bf(v[1]); o[2] = f2bf(v[2]); o[3] = f2bf(v[3]);
    *(__attribute__((ext_vector_type(4))) short*)&out[i] =
        *(__attribute__((ext_vector_type(4))) short*)o;
}

// LDS-tiled transpose+cast: out[n*K+k] = bf16(in[k*N+n]); coalesced both sides.
__global__ __launch_bounds__(256) void wtrans(const float* __restrict__ in,
                                              unsigned short* __restrict__ out,
                                              int K, int N) {
    __shared__ unsigned short t[32 * 33];
    const int nb = blockIdx.x * 32, kb = blockIdx.y * 32;
    const int c = threadIdx.x & 31, rr = threadIdx.x >> 5;
#pragma unroll
    for (int it = 0; it < 4; ++it) {
        int r = it * 8 + rr;
        t[c * 33 + r] = f2bf(in[(long)(kb + r) * N + nb + c]);
    }
    __syncthreads();
#pragma unroll
    for (int it = 0; it < 4; ++it) {
        int r = it * 8 + rr;
        out[(long)(nb + r) * K + kb + c] = t[r * 33 + c];
    }
}

// GEMM: C(MxN) = A(MxK,bf16) * BT(NxK,bf16)^T, fp32/bf16 out.
// Tile TMx128, BK=64, global_load_lds(16) staging, XOR-swizzled LDS layout.
template <int TM, bool F32OUT>
__global__ __launch_bounds__(256, TM == 64 ? 4 : 3)
void gemm_sw(const unsigned short* __restrict__ A,
             const unsigned short* __restrict__ BT,
             void* __restrict__ Cv, int M, int N, int K) {
    __shared__ unsigned short As[TM * 64];
    __shared__ unsigned short Bs[128 * 64];
    const int tid = threadIdx.x;
    const int wid = tid >> 6, lane = tid & 63;
    const int l15 = lane & 15, quad = lane >> 4;
    const int wm = (wid >> 1) * (TM / 2), wn = (wid & 1) * 64;
    const int row0 = blockIdx.x * TM, col0 = blockIdx.y * 128;
    constexpr int MI = TM / 32;  // m-frags per wave

    float4v acc[MI][4];
    float4v z;
    z[0] = z[1] = z[2] = z[3] = 0.0f;
    for (int mi = 0; mi < MI; ++mi)
        for (int ni = 0; ni < 4; ++ni) acc[mi][ni] = z;

    const int r_ld = lane >> 3;                          // 0..7 row in chunk16
    const int swz_ld = ((lane & 7) ^ (lane >> 3)) * 8;   // swizzled source col
    const int sw = l15 & 7;                              // read-side swizzle

    for (int kb = 0; kb < K; kb += 64) {
        __syncthreads();
#pragma unroll
        for (int c = 0; c < 4; ++c) {
            int chunk = c * 4 + wid;  // 16 chunks of 8 rows (B); TM/8 for A
            int r = chunk * 8 + r_ld;
            __builtin_amdgcn_global_load_lds(
                (gu32*)&BT[(long)(col0 + r) * K + kb + swz_ld],
                (lu32*)&Bs[chunk * 512], 16, 0, 0);
            if (c < MI)
                __builtin_amdgcn_global_load_lds(
                    (gu32*)&A[(long)(row0 + r) * K + kb + swz_ld],
                    (lu32*)&As[chunk * 512], 16, 0, 0);
        }
        __syncthreads();
#pragma unroll
        for (int kk = 0; kk < 64; kk += 32) {
            short8 af[MI], bf[4];
#pragma unroll
            for (int i = 0; i < MI; ++i)
                af[i] = *(const short8*)
                    &As[(wm + i * 16 + l15) * 64 + ((((kk >> 3) + quad) ^ sw) << 3)];
#pragma unroll
            for (int i = 0; i < 4; ++i)
                bf[i] = *(const short8*)
                    &Bs[(wn + i * 16 + l15) * 64 + ((((kk >> 3) + quad) ^ sw) << 3)];
#pragma unroll
            for (int mi = 0; mi < MI; ++mi)
#pragma unroll
                for (int ni = 0; ni < 4; ++ni)
                    acc[mi][ni] = __builtin_amdgcn_mfma_f32_16x16x32_bf16(
                        af[mi], bf[ni], acc[mi][ni], 0, 0, 0);
        }
    }
#pragma unroll
    for (int mi = 0; mi < MI; ++mi)
#pragma unroll
        for (int ni = 0; ni < 4; ++ni)
#pragma unroll
            for (int r = 0; r < 4; ++r) {
                int m = row0 + wm + mi * 16 + quad * 4 + r;
                int n = col0 + wn + ni * 16 + l15;
                if (F32OUT)
                    ((float*)Cv)[(long)m * N + n] = acc[mi][ni][r];
                else
                    ((unsigned short*)Cv)[(long)m * N + n] = f2bf(acc[mi][ni][r]);
            }
}

// RoPE: one thread per (row, i-pair); trig once, applied to all 40 heads.
// Q heads (0..31) pre-scaled by QSCALE so flash can use raw 2^x.
__global__ __launch_bounds__(256) void rope2(unsigned short* __restrict__ qkv) {
    const int i = threadIdx.x & 31;
    const int row = blockIdx.x * 8 + (threadIdx.x >> 5);
    const int s = row & (S_LEN - 1);
    float freq = __expf(-0.28782313f * (float)i);  // 10000^(-i/32)
    float ang = (float)s * freq;
    float c = cosf(ang), sn = sinf(ang);
    unsigned* p = (unsigned*)qkv + ((long)row * QKV_N + 2 * i) / 2;
#pragma unroll
    for (int head = 0; head < 40; ++head) {
        const float qs = (head < 32) ? QSCALE : 1.0f;
        unsigned v = p[head * 32];
        float xr = bf2f((unsigned short)(v & 0xffff));
        float xi = bf2f((unsigned short)(v >> 16));
        unsigned short lo = f2bf((xr * c - xi * sn) * qs);
        unsigned short hi = f2bf((xr * sn + xi * c) * qs);
        p[head * 32] = (unsigned)lo | ((unsigned)hi << 16);
    }
}

// V transpose: qkv V region -> Vt[b*8+kh][d=64][s=2048]. Dword-pair trick.
__global__ __launch_bounds__(256) void vtrans(const unsigned short* __restrict__ qkv,
                                              unsigned short* __restrict__ Vt) {
    __shared__ unsigned t[64 * 33];
    const int st = blockIdx.x * 64, kh = blockIdx.y, b = blockIdx.z;
    const int tid = threadIdx.x;
    {
        const int r2 = tid >> 3, dbase = (tid & 7) * 8;
        const unsigned short* src =
            qkv + ((long)(b * S_LEN + st + 2 * r2)) * QKV_N + D_MODEL + KV_D + kh * HD + dbase;
        short8 lo = *(const short8*)src;
        short8 hi = *(const short8*)(src + QKV_N);
#pragma unroll
        for (int j = 0; j < 8; ++j)
            t[(dbase + j) * 33 + r2] =
                (unsigned)(unsigned short)lo[j] | ((unsigned)(unsigned short)hi[j] << 16);
    }
    __syncthreads();
    {
        const int d = tid >> 2, sb = (tid & 3) * 8;
        unsigned short o[16];
#pragma unroll
        for (int jj = 0; jj < 8; ++jj) {
            unsigned v = t[d * 33 + sb + jj];
            o[2 * jj] = (unsigned short)(v & 0xffff);
            o[2 * jj + 1] = (unsigned short)(v >> 16);
        }
        unsigned short* dst =
            Vt + ((long)((b * 8 + kh) * 64 + d)) * S_LEN + st + sb * 2;
        *(short8*)dst = *(short8*)&o[0];
        *(short8*)(dst + 8) = *(short8*)&o[8];
    }
}

// Flash v6: 32x32x16 MFMA, swapped QK^T (mfma(K,Q) -> P^T in registers),
// in-register P->bf16 via cvt_pk + permlane32_swap (no LDS P relay),
// PV as O^T = V^T P^T (Vt is [d][s], contiguous A-frags).
// 4 waves x 32 q-rows = 128-row q-tile per 256-thread block; 1024 blocks
// = 4/CU, 16 waves/CU. K/V LDS reads amortize over 2x q-rows vs v5.
// K/V double-buffered, DMA-prefetched (one barrier/iter). XOR-swizzled LDS.
// O^T transposed back via per-wave LDS staging (swizzled) + coalesced store.
// Causal balance: qt permutation w/ uniform 4-window and (r,r+8) sums.
__global__ __launch_bounds__(256, 4) void flash6(const unsigned short* __restrict__ qkv,
                                                 const unsigned short* __restrict__ Vt,
                                                 unsigned short* __restrict__ O) {
    __shared__ unsigned short Ks[2][64 * 64];  // [key][d], swizzled chunks
    __shared__ unsigned short Vs[2][64 * 64];  // [d][key], swizzled chunks

    const int tid = threadIdx.x, w = tid >> 6, lane = tid & 63;
    const int l31 = lane & 31, hi = lane >> 5;
    const int r7 = l31 & 7;
    const int h = blockIdx.y, b = blockIdx.z;
    const int kh = h >> 2, bkh = b * 8 + kh;

    // load-balance map: nibble-packed permutation of 0..15
    const unsigned bx = blockIdx.x;
    const int qt = (int)(((bx < 8) ? (0x97C2B5E0u >> (4 * bx))
                                   : (0x683D4A1Fu >> (4 * (bx - 8)))) & 15u);
    const int row_w = qt * 128 + w * 32;
    const int nkt = 2 * qt + 2;

    // DMA staging: wave w covers rows {w*8+sr, 32+w*8+sr}, phys chunk lane&7,
    // source col pre-swizzled so LDS stays linear for the DMA.
    const int sr = lane >> 3;
    const int sc = ((lane & 7) ^ sr) * 8;
    const int kr0 = w * 8 + sr, kr1 = 32 + w * 8 + sr;
    const unsigned short* Kg =
        qkv + (long)b * S_LEN * QKV_N + D_MODEL + kh * HD + sc;
    const unsigned short* Vg = Vt + ((long)bkh * 64) * S_LEN + sc;

#define STAGE6(buf, kb)                                                              \
    do {                                                                             \
        __builtin_amdgcn_global_load_lds((gu32*)&Kg[(long)((kb) + kr0) * QKV_N],     \
                                         (lu32*)&Ks[buf][w * 512], 16, 0, 0);        \
        __builtin_amdgcn_global_load_lds((gu32*)&Kg[(long)((kb) + kr1) * QKV_N],     \
                                         (lu32*)&Ks[buf][2048 + w * 512], 16, 0, 0); \
        __builtin_amdgcn_global_load_lds((gu32*)&Vg[(long)kr0 * S_LEN + (kb)],       \
                                         (lu32*)&Vs[buf][w * 512], 16, 0, 0);        \
        __builtin_amdgcn_global_load_lds((gu32*)&Vg[(long)kr1 * S_LEN + (kb)],       \
                                         (lu32*)&Vs[buf][2048 + w * 512], 16, 0, 0); \
    } while (0)

    // Q B-frags: lane holds col q = l31, d-rows ks*16 + hi*8 + 0..7
    short8 aq[4];
    {
        const long qbase = ((long)(b * S_LEN) + row_w + l31) * QKV_N + h * HD + hi * 8;
#pragma unroll
        for (int ks = 0; ks < 4; ++ks) aq[ks] = *(const short8*)&qkv[qbase + ks * 16];
    }

    f32x16 oacc[2] = {};
    float lp = 0.0f;

    STAGE6(0, 0);
    __syncthreads();

    for (int kti = 0; kti < nkt; ++kti) {
        const int k0 = kti * 64;
        const int cur = kti & 1;
        if (kti + 1 < nkt) STAGE6(cur ^ 1, k0 + 64);

        if (row_w + 31 >= k0) {  // wave-uniform: skip fully-masked tiles
            const bool mb = (k0 + 63 > row_w);
#pragma unroll
            for (int kb2 = 0; kb2 < 2; ++kb2) {
                // QK^T swapped: A = K rows(key)=kb2*32+l31, B = Q
                short8 kf[4];
#pragma unroll
                for (int ks = 0; ks < 4; ++ks)
                    kf[ks] = *(const short8*)
                        &Ks[cur][(kb2 * 32 + l31) * 64 + (((ks * 2 + hi) ^ r7) << 3)];
                f32x16 s = {};
                __builtin_amdgcn_s_setprio(1);
#pragma unroll
                for (int ks = 0; ks < 4; ++ks)
                    s = __builtin_amdgcn_mfma_f32_32x32x16_bf16(kf[ks], aq[ks], s, 0, 0, 0);
                __builtin_amdgcn_s_setprio(0);

                // softmax: s row = key = kb2*32 + (r&3)+8*(r>>2)+4*hi, col q = l31
                const int qrel = row_w + l31 - k0 - kb2 * 32 - 4 * hi;
#pragma unroll
                for (int r = 0; r < 16; ++r) {
                    float v = s[r];
                    if (mb && ((r & 3) + 8 * (r >> 2) > qrel)) v = -1e4f;
                    float p = PEXP(v);
                    lp += p;
                    s[r] = p;
                }

                // P^T B-frags in-register (cvt_pk + permlane32_swap), then PV
#pragma unroll
                for (int ksl = 0; ksl < 2; ++ksl) {
                    const int g = ksl * 8;
                    unsigned ca = cvt_pk_bf16(s[g + 0], s[g + 1]);
                    unsigned cb = cvt_pk_bf16(s[g + 2], s[g + 3]);
                    unsigned cc = cvt_pk_bf16(s[g + 4], s[g + 5]);
                    unsigned cd = cvt_pk_bf16(s[g + 6], s[g + 7]);
                    unsigned dw0, dw1, dw2, dw3;
                    pl32swap(ca, cc, dw0, dw2);
                    pl32swap(cb, cd, dw1, dw3);
                    union { unsigned u[4]; short8 v8; } pf;
                    pf.u[0] = dw0; pf.u[1] = dw1; pf.u[2] = dw2; pf.u[3] = dw3;
                    const int lc = kb2 * 4 + ksl * 2 + hi;
                    __builtin_amdgcn_s_setprio(1);
#pragma unroll
                    for (int dblk = 0; dblk < 2; ++dblk) {
                        short8 vf = *(const short8*)
                            &Vs[cur][(dblk * 32 + l31) * 64 + ((lc ^ r7) << 3)];
                        oacc[dblk] = __builtin_amdgcn_mfma_f32_32x32x16_bf16(
                            vf, pf.v8, oacc[dblk], 0, 0, 0);
                    }
                    __builtin_amdgcn_s_setprio(0);
                }
            }
        }
        __syncthreads();  // buf cur^1 safe to overwrite next iter
    }

    // epilogue: l = lp(self) + lp(partner l^32); O^T -> O via per-wave LDS
    float linv = 1.0f / (lp + __shfl_xor(lp, 32));
    unsigned short* Oe = &Ks[0][0] + w * 2048;  // 32q x 64d, chunk-swizzled
#pragma unroll
    for (int dblk = 0; dblk < 2; ++dblk)
#pragma unroll
        for (int rq = 0; rq < 4; ++rq) {
            // d = dblk*32 + rq*8 + hi*4 + (0..3), q = l31
            unsigned plo = cvt_pk_bf16(oacc[dblk][rq * 4 + 0] * linv,
                                       oacc[dblk][rq * 4 + 1] * linv);
            unsigned phi = cvt_pk_bf16(oacc[dblk][rq * 4 + 2] * linv,
                                       oacc[dblk][rq * 4 + 3] * linv);
            uint2v wv;
            wv[0] = plo; wv[1] = phi;
            int e = l31 * 64 + (((rq + 4 * dblk) ^ r7) << 3) + hi * 4;
            *(uint2v*)&Oe[e] = wv;
        }
    // in-wave write->read; no barrier needed (private region)
#pragma unroll
    for (int i = 0; i < 4; ++i) {
        int q2 = i * 8 + (lane >> 3);
        int e = q2 * 64 + (((lane & 7) ^ (lane >> 3)) << 3);
        short8 ov = *(const short8*)&Oe[e];
        long orow = ((long)(b * S_LEN) + row_w + q2) * D_MODEL + h * HD + (lane & 7) * 8;
        *(short8*)&O[orow] = ov;
    }
#undef STAGE6
}

extern "C" void kernel_launch(void* const* d_in, const int* in_sizes, int n_in,
                              void* d_out, int out_size, void* d_ws, size_t ws_size,
                              hipStream_t stream) {
    const float* x  = (const float*)d_in[0];
    const float* wq = (const float*)d_in[n_in - 4];
    const float* wk = (const float*)d_in[n_in - 3];
    const float* wv = (const float*)d_in[n_in - 2];
    const float* wo = (const float*)d_in[n_in - 1];
    float* out = (float*)d_out;

    unsigned short* ws    = (unsigned short*)d_ws;
    unsigned short* xb    = ws;                                   // 4096 x 2048
    unsigned short* Obuf  = ws;                                   // reuses xb
    unsigned short* qkv   = xb + (long)BATCH * S_LEN * D_MODEL;   // 4096 x 3072
    unsigned short* woT   = qkv + (long)BATCH * S_LEN * QKV_N;    // 2048 x 2048
    unsigned short* wqkvT = woT + (long)D_MODEL * D_MODEL;        // 3072 x 2048
    unsigned short* Vt    = wqkvT;                                // reuses wqkvT

    const int M = BATCH * S_LEN;  // 4096
    const long xn = (long)M * D_MODEL;

    cast_f32_bf16<<<(int)(xn / 4 / 256), 256, 0, stream>>>(x, xb, xn);

    wtrans<<<dim3(D_MODEL / 32, D_MODEL / 32), 256, 0, stream>>>(wq, wqkvT, D_MODEL, D_MODEL);
    wtrans<<<dim3(KV_D / 32, D_MODEL / 32), 256, 0, stream>>>(wk, wqkvT + (long)D_MODEL * D_MODEL, D_MODEL, KV_D);
    wtrans<<<dim3(KV_D / 32, D_MODEL / 32), 256, 0, stream>>>(wv, wqkvT + (long)(D_MODEL + KV_D) * D_MODEL, D_MODEL, KV_D);
    wtrans<<<dim3(D_MODEL / 32, D_MODEL / 32), 256, 0, stream>>>(wo, woT, D_MODEL, D_MODEL);

    // QKV projection: 128x128 swizzled tiles (768 blocks = 3/CU)
    gemm_sw<128, false><<<dim3(M / 128, QKV_N / 128), 256, 0, stream>>>(
        xb, wqkvT, qkv, M, QKV_N, D_MODEL);

    rope2<<<M / 8, 256, 0, stream>>>(qkv);

    vtrans<<<dim3(S_LEN / 64, NKV, BATCH), 256, 0, stream>>>(qkv, Vt);

    flash6<<<dim3(16, NH, BATCH), 256, 0, stream>>>(qkv, Vt, Obuf);

    // out projection: 64x128 swizzled tiles (1024 blocks = 4/CU)
    gemm_sw<64, true><<<dim3(M / 64, D_MODEL / 128), 256, 0, stream>>>(
        Obuf, woT, out, M, D_MODEL, D_MODEL);
}

// Round 3
// 302.859 us; speedup vs baseline: 1.1031x; 1.1031x over previous
//
#include <hip/hip_runtime.h>
#include <hip/hip_bf16.h>

// Attention: B=2, S=2048, D=2048, NH=32, NKV=8, HD=64, causal, RoPE, GQA.
// Inputs fp32, OUTPUT fp32. Internal bf16 MFMA, fp32 accumulate.
//
// ws layout (63 MB, bf16 elems):
//   xb/Obuf :  8,388,608 (4096x2048) — xb dead after QKV GEMM, reused as Obuf
//   qkv     : 12,582,912 (4096x3072)
//   woT     :  4,194,304 (2048x2048)
//   wqkvT/Vt:  6,291,456 — wqkvT dead after QKV GEMM, reused as Vt[b*8+kh][64][2048]

#define S_LEN 2048
#define BATCH 2
#define D_MODEL 2048
#define NH 32
#define NKV 8
#define HD 64
#define KV_D (NKV * HD)            // 512
#define QKV_N (D_MODEL + 2 * KV_D) // 3072

typedef __attribute__((ext_vector_type(8))) short short8;
typedef __attribute__((ext_vector_type(4))) float float4v;
typedef __attribute__((ext_vector_type(16))) float f32x16;
typedef __attribute__((ext_vector_type(2))) unsigned uint2v;

typedef __attribute__((address_space(1))) const unsigned int gu32;
typedef __attribute__((address_space(3))) unsigned int lu32;

// Q is pre-scaled by 0.125*log2(e) in rope2; scores then feed v_exp_f32 (2^x) raw.
#if __has_builtin(__builtin_amdgcn_exp2f)
#define PEXP(x) __builtin_amdgcn_exp2f(x)
#else
#define PEXP(x) __expf((x) * 0.69314718f)
#endif
#define QSCALE 0.18033688f  // 0.125 * log2(e)

__device__ __forceinline__ float bf2f(unsigned short u) {
    unsigned x = ((unsigned)u) << 16;
    return __builtin_bit_cast(float, x);
}
__device__ __forceinline__ unsigned short f2bf(float f) {
    unsigned u = __builtin_bit_cast(unsigned, f);
    unsigned r = (u + 0x7fffu + ((u >> 16) & 1u)) >> 16;
    return (unsigned short)r;
}

// packed f32x2 -> bf16x2 (RNE), single instruction
__device__ __forceinline__ unsigned cvt_pk_bf16(float a, float b) {
    unsigned r;
    asm("v_cvt_pk_bf16_f32 %0, %1, %2" : "=v"(r) : "v"(a), "v"(b));
    return r;
}

// permlane32_swap(a, b) -> (x, y): x = [lo: a(self) | hi: b(partner)],
// y = [lo: a(partner) | hi: b(self)]
__device__ __forceinline__ void pl32swap(unsigned a, unsigned b,
                                         unsigned& x, unsigned& y) {
#if __has_builtin(__builtin_amdgcn_permlane32_swap)
    uint2v r = __builtin_amdgcn_permlane32_swap(a, b, false, false);
    x = r[0];
    y = r[1];
#else
    unsigned pa = (unsigned)__shfl_xor((int)a, 32);
    unsigned pb = (unsigned)__shfl_xor((int)b, 32);
    bool lo = (threadIdx.x & 63) < 32;
    x = lo ? a : pb;
    y = lo ? pa : b;
#endif
}

// fp32 -> bf16 elementwise cast, 4 elems/thread.
__global__ void cast_f32_bf16(const float* __restrict__ in,
                              unsigned short* __restrict__ out, long n) {
    long i = ((long)blockIdx.x * 256 + threadIdx.x) * 4;
    if (i + 3 >= n) return;
    const float4v v = *(const float4v*)&in[i];
    unsigned short o[4];
    o[0] = f2bf(v[0]); o[1] = f2bf(v[1]); o[2] = f2bf(v[2]); o[3] = f2bf(v[3]);
    *(__attribute__((ext_vector_type(4))) short*)&out[i] =
        *(__attribute__((ext_vector_type(4))) short*)o;
}

// LDS-tiled transpose+cast: out[n*K+k] = bf16(in[k*N+n]); coalesced both sides.
__global__ __launch_bounds__(256) void wtrans(const float* __restrict__ in,
                                              unsigned short* __restrict__ out,
                                              int K, int N) {
    __shared__ unsigned short t[32 * 33];
    const int nb = blockIdx.x * 32, kb = blockIdx.y * 32;
    const int c = threadIdx.x & 31, rr = threadIdx.x >> 5;
#pragma unroll
    for (int it = 0; it < 4; ++it) {
        int r = it * 8 + rr;
        t[c * 33 + r] = f2bf(in[(long)(kb + r) * N + nb + c]);
    }
    __syncthreads();
#pragma unroll
    for (int it = 0; it < 4; ++it) {
        int r = it * 8 + rr;
        out[(long)(nb + r) * K + kb + c] = t[r * 33 + c];
    }
}

// GEMM: C(MxN) = A(MxK,bf16) * BT(NxK,bf16)^T, fp32/bf16 out.
// Tile TMx128, BK=64, global_load_lds(16) staging, XOR-swizzled LDS layout.
template <int TM, bool F32OUT>
__global__ __launch_bounds__(256, TM == 64 ? 4 : 3)
void gemm_sw(const unsigned short* __restrict__ A,
             const unsigned short* __restrict__ BT,
             void* __restrict__ Cv, int M, int N, int K) {
    __shared__ unsigned short As[TM * 64];
    __shared__ unsigned short Bs[128 * 64];
    const int tid = threadIdx.x;
    const int wid = tid >> 6, lane = tid & 63;
    const int l15 = lane & 15, quad = lane >> 4;
    const int wm = (wid >> 1) * (TM / 2), wn = (wid & 1) * 64;
    const int row0 = blockIdx.x * TM, col0 = blockIdx.y * 128;
    constexpr int MI = TM / 32;  // m-frags per wave

    float4v acc[MI][4];
    float4v z;
    z[0] = z[1] = z[2] = z[3] = 0.0f;
    for (int mi = 0; mi < MI; ++mi)
        for (int ni = 0; ni < 4; ++ni) acc[mi][ni] = z;

    const int r_ld = lane >> 3;                          // 0..7 row in chunk16
    const int swz_ld = ((lane & 7) ^ (lane >> 3)) * 8;   // swizzled source col
    const int sw = l15 & 7;                              // read-side swizzle

    for (int kb = 0; kb < K; kb += 64) {
        __syncthreads();
#pragma unroll
        for (int c = 0; c < 4; ++c) {
            int chunk = c * 4 + wid;  // 16 chunks of 8 rows (B); TM/8 for A
            int r = chunk * 8 + r_ld;
            __builtin_amdgcn_global_load_lds(
                (gu32*)&BT[(long)(col0 + r) * K + kb + swz_ld],
                (lu32*)&Bs[chunk * 512], 16, 0, 0);
            if (c < MI)
                __builtin_amdgcn_global_load_lds(
                    (gu32*)&A[(long)(row0 + r) * K + kb + swz_ld],
                    (lu32*)&As[chunk * 512], 16, 0, 0);
        }
        __syncthreads();
#pragma unroll
        for (int kk = 0; kk < 64; kk += 32) {
            short8 af[MI], bf[4];
#pragma unroll
            for (int i = 0; i < MI; ++i)
                af[i] = *(const short8*)
                    &As[(wm + i * 16 + l15) * 64 + ((((kk >> 3) + quad) ^ sw) << 3)];
#pragma unroll
            for (int i = 0; i < 4; ++i)
                bf[i] = *(const short8*)
                    &Bs[(wn + i * 16 + l15) * 64 + ((((kk >> 3) + quad) ^ sw) << 3)];
#pragma unroll
            for (int mi = 0; mi < MI; ++mi)
#pragma unroll
                for (int ni = 0; ni < 4; ++ni)
                    acc[mi][ni] = __builtin_amdgcn_mfma_f32_16x16x32_bf16(
                        af[mi], bf[ni], acc[mi][ni], 0, 0, 0);
        }
    }
#pragma unroll
    for (int mi = 0; mi < MI; ++mi)
#pragma unroll
        for (int ni = 0; ni < 4; ++ni)
#pragma unroll
            for (int r = 0; r < 4; ++r) {
                int m = row0 + wm + mi * 16 + quad * 4 + r;
                int n = col0 + wn + ni * 16 + l15;
                if (F32OUT)
                    ((float*)Cv)[(long)m * N + n] = acc[mi][ni][r];
                else
                    ((unsigned short*)Cv)[(long)m * N + n] = f2bf(acc[mi][ni][r]);
            }
}

// RoPE: one thread per (row, i-pair); trig once, applied to all 40 heads.
// Q heads (0..31) pre-scaled by QSCALE so flash can use raw 2^x.
__global__ __launch_bounds__(256) void rope2(unsigned short* __restrict__ qkv) {
    const int i = threadIdx.x & 31;
    const int row = blockIdx.x * 8 + (threadIdx.x >> 5);
    const int s = row & (S_LEN - 1);
    float freq = __expf(-0.28782313f * (float)i);  // 10000^(-i/32)
    float ang = (float)s * freq;
    float c = cosf(ang), sn = sinf(ang);
    unsigned* p = (unsigned*)qkv + ((long)row * QKV_N + 2 * i) / 2;
#pragma unroll
    for (int head = 0; head < 40; ++head) {
        const float qs = (head < 32) ? QSCALE : 1.0f;
        unsigned v = p[head * 32];
        float xr = bf2f((unsigned short)(v & 0xffff));
        float xi = bf2f((unsigned short)(v >> 16));
        unsigned short lo = f2bf((xr * c - xi * sn) * qs);
        unsigned short hi = f2bf((xr * sn + xi * c) * qs);
        p[head * 32] = (unsigned)lo | ((unsigned)hi << 16);
    }
}

// V transpose: qkv V region -> Vt[b*8+kh][d=64][s=2048]. Dword-pair trick.
__global__ __launch_bounds__(256) void vtrans(const unsigned short* __restrict__ qkv,
                                              unsigned short* __restrict__ Vt) {
    __shared__ unsigned t[64 * 33];
    const int st = blockIdx.x * 64, kh = blockIdx.y, b = blockIdx.z;
    const int tid = threadIdx.x;
    {
        const int r2 = tid >> 3, dbase = (tid & 7) * 8;
        const unsigned short* src =
            qkv + ((long)(b * S_LEN + st + 2 * r2)) * QKV_N + D_MODEL + KV_D + kh * HD + dbase;
        short8 lo = *(const short8*)src;
        short8 hi = *(const short8*)(src + QKV_N);
#pragma unroll
        for (int j = 0; j < 8; ++j)
            t[(dbase + j) * 33 + r2] =
                (unsigned)(unsigned short)lo[j] | ((unsigned)(unsigned short)hi[j] << 16);
    }
    __syncthreads();
    {
        const int d = tid >> 2, sb = (tid & 3) * 8;
        unsigned short o[16];
#pragma unroll
        for (int jj = 0; jj < 8; ++jj) {
            unsigned v = t[d * 33 + sb + jj];
            o[2 * jj] = (unsigned short)(v & 0xffff);
            o[2 * jj + 1] = (unsigned short)(v >> 16);
        }
        unsigned short* dst =
            Vt + ((long)((b * 8 + kh) * 64 + d)) * S_LEN + st + sb * 2;
        *(short8*)dst = *(short8*)&o[0];
        *(short8*)(dst + 8) = *(short8*)&o[8];
    }
}

// Flash v7: flash6's 32x32 swapped-QK / in-register-softmax structure inside
// flash5's BALANCED shell: each block runs q-tiles (qtA, 15-qtA) sequentially
// -> exactly 34 k-iters/block (uniform; fixes v6's resident-grid imbalance,
// occupancy 22% from CU busy ~ max(nkt) not mean). Grid 8x32x2 = 512 blocks
// of 256 thr = 2 blocks/CU, 8 waves/CU.
// Inner: mfma(K,Q) -> P^T in regs; cvt_pk + permlane32_swap -> bf16 B-frags
// (no LDS P relay); PV as O^T = V^T P^T; K/V dbuf + DMA prefetch; XOR-swizzle.
__global__ __launch_bounds__(256, 4) void flash7(const unsigned short* __restrict__ qkv,
                                                 const unsigned short* __restrict__ Vt,
                                                 unsigned short* __restrict__ O) {
    __shared__ unsigned short Ks[2][64 * 64];  // [key][d], swizzled chunks
    __shared__ unsigned short Vs[2][64 * 64];  // [d][key], swizzled chunks

    const int tid = threadIdx.x, w = tid >> 6, lane = tid & 63;
    const int l31 = lane & 31, hi = lane >> 5;
    const int r7 = l31 & 7;
    const int h = blockIdx.y, b = blockIdx.z;
    const int kh = h >> 2, bkh = b * 8 + kh;
    const int qtA = blockIdx.x;  // 0..7

    // DMA staging: wave w covers rows {w*8+sr, 32+w*8+sr}, phys chunk lane&7,
    // source col pre-swizzled so LDS stays linear for the DMA.
    const int sr = lane >> 3;
    const int sc = ((lane & 7) ^ sr) * 8;
    const int kr0 = w * 8 + sr, kr1 = 32 + w * 8 + sr;
    const unsigned short* Kg =
        qkv + (long)b * S_LEN * QKV_N + D_MODEL + kh * HD + sc;
    const unsigned short* Vg = Vt + ((long)bkh * 64) * S_LEN + sc;

#define STAGE7(buf, kb)                                                              \
    do {                                                                             \
        __builtin_amdgcn_global_load_lds((gu32*)&Kg[(long)((kb) + kr0) * QKV_N],     \
                                         (lu32*)&Ks[buf][w * 512], 16, 0, 0);        \
        __builtin_amdgcn_global_load_lds((gu32*)&Kg[(long)((kb) + kr1) * QKV_N],     \
                                         (lu32*)&Ks[buf][2048 + w * 512], 16, 0, 0); \
        __builtin_amdgcn_global_load_lds((gu32*)&Vg[(long)kr0 * S_LEN + (kb)],       \
                                         (lu32*)&Vs[buf][w * 512], 16, 0, 0);        \
        __builtin_amdgcn_global_load_lds((gu32*)&Vg[(long)kr1 * S_LEN + (kb)],       \
                                         (lu32*)&Vs[buf][2048 + w * 512], 16, 0, 0); \
    } while (0)

    for (int tsel = 0; tsel < 2; ++tsel) {
        const int qt = tsel ? (15 - qtA) : qtA;
        const int row_w = qt * 128 + w * 32;
        const int nkt = 2 * qt + 2;

        // Q B-frags: lane holds col q = l31, d-rows ks*16 + hi*8 + 0..7
        short8 aq[4];
        {
            const long qbase = ((long)(b * S_LEN) + row_w + l31) * QKV_N + h * HD + hi * 8;
#pragma unroll
            for (int ks = 0; ks < 4; ++ks) aq[ks] = *(const short8*)&qkv[qbase + ks * 16];
        }

        f32x16 oacc[2] = {};
        float lp = 0.0f;

        STAGE7(0, 0);
        __syncthreads();

        for (int kti = 0; kti < nkt; ++kti) {
            const int k0 = kti * 64;
            const int cur = kti & 1;
            if (kti + 1 < nkt) STAGE7(cur ^ 1, k0 + 64);

            if (row_w + 31 >= k0) {  // wave-uniform: skip fully-masked tiles
                const bool mb = (k0 + 63 > row_w);
#pragma unroll
                for (int kb2 = 0; kb2 < 2; ++kb2) {
                    // QK^T swapped: A = K rows(key)=kb2*32+l31, B = Q
                    short8 kf[4];
#pragma unroll
                    for (int ks = 0; ks < 4; ++ks)
                        kf[ks] = *(const short8*)
                            &Ks[cur][(kb2 * 32 + l31) * 64 + (((ks * 2 + hi) ^ r7) << 3)];
                    f32x16 s = {};
                    __builtin_amdgcn_s_setprio(1);
#pragma unroll
                    for (int ks = 0; ks < 4; ++ks)
                        s = __builtin_amdgcn_mfma_f32_32x32x16_bf16(kf[ks], aq[ks], s, 0, 0, 0);
                    __builtin_amdgcn_s_setprio(0);

                    // softmax: s row = key = kb2*32 + (r&3)+8*(r>>2)+4*hi, col q = l31
                    const int qrel = row_w + l31 - k0 - kb2 * 32 - 4 * hi;
#pragma unroll
                    for (int r = 0; r < 16; ++r) {
                        float v = s[r];
                        if (mb && ((r & 3) + 8 * (r >> 2) > qrel)) v = -1e4f;
                        float p = PEXP(v);
                        lp += p;
                        s[r] = p;
                    }

                    // P^T B-frags in-register (cvt_pk + permlane32_swap), then PV
#pragma unroll
                    for (int ksl = 0; ksl < 2; ++ksl) {
                        const int g = ksl * 8;
                        unsigned ca = cvt_pk_bf16(s[g + 0], s[g + 1]);
                        unsigned cb = cvt_pk_bf16(s[g + 2], s[g + 3]);
                        unsigned cc = cvt_pk_bf16(s[g + 4], s[g + 5]);
                        unsigned cd = cvt_pk_bf16(s[g + 6], s[g + 7]);
                        unsigned dw0, dw1, dw2, dw3;
                        pl32swap(ca, cc, dw0, dw2);
                        pl32swap(cb, cd, dw1, dw3);
                        union { unsigned u[4]; short8 v8; } pf;
                        pf.u[0] = dw0; pf.u[1] = dw1; pf.u[2] = dw2; pf.u[3] = dw3;
                        const int lc = kb2 * 4 + ksl * 2 + hi;
                        __builtin_amdgcn_s_setprio(1);
#pragma unroll
                        for (int dblk = 0; dblk < 2; ++dblk) {
                            short8 vf = *(const short8*)
                                &Vs[cur][(dblk * 32 + l31) * 64 + ((lc ^ r7) << 3)];
                            oacc[dblk] = __builtin_amdgcn_mfma_f32_32x32x16_bf16(
                                vf, pf.v8, oacc[dblk], 0, 0, 0);
                        }
                        __builtin_amdgcn_s_setprio(0);
                    }
                }
            }
            __syncthreads();  // buf cur^1 safe to overwrite next iter
        }

        // epilogue: l = lp(self) + lp(partner l^32); O^T -> O via per-wave LDS
        float linv = 1.0f / (lp + __shfl_xor(lp, 32));
        unsigned short* Oe = &Ks[0][0] + w * 2048;  // 32q x 64d, chunk-swizzled
#pragma unroll
        for (int dblk = 0; dblk < 2; ++dblk)
#pragma unroll
            for (int rq = 0; rq < 4; ++rq) {
                // d = dblk*32 + rq*8 + hi*4 + (0..3), q = l31
                unsigned plo = cvt_pk_bf16(oacc[dblk][rq * 4 + 0] * linv,
                                           oacc[dblk][rq * 4 + 1] * linv);
                unsigned phi = cvt_pk_bf16(oacc[dblk][rq * 4 + 2] * linv,
                                           oacc[dblk][rq * 4 + 3] * linv);
                uint2v wv;
                wv[0] = plo; wv[1] = phi;
                int e = l31 * 64 + (((rq + 4 * dblk) ^ r7) << 3) + hi * 4;
                *(uint2v*)&Oe[e] = wv;
            }
        // in-wave write->read; no barrier needed (private region)
#pragma unroll
        for (int i = 0; i < 4; ++i) {
            int q2 = i * 8 + (lane >> 3);
            int e = q2 * 64 + (((lane & 7) ^ (lane >> 3)) << 3);
            short8 ov = *(const short8*)&Oe[e];
            long orow = ((long)(b * S_LEN) + row_w + q2) * D_MODEL + h * HD + (lane & 7) * 8;
            *(short8*)&O[orow] = ov;
        }
        __syncthreads();  // protect Oe scratch (in Ks) from next tsel's DMA
    }
#undef STAGE7
}

extern "C" void kernel_launch(void* const* d_in, const int* in_sizes, int n_in,
                              void* d_out, int out_size, void* d_ws, size_t ws_size,
                              hipStream_t stream) {
    const float* x  = (const float*)d_in[0];
    const float* wq = (const float*)d_in[n_in - 4];
    const float* wk = (const float*)d_in[n_in - 3];
    const float* wv = (const float*)d_in[n_in - 2];
    const float* wo = (const float*)d_in[n_in - 1];
    float* out = (float*)d_out;

    unsigned short* ws    = (unsigned short*)d_ws;
    unsigned short* xb    = ws;                                   // 4096 x 2048
    unsigned short* Obuf  = ws;                                   // reuses xb
    unsigned short* qkv   = xb + (long)BATCH * S_LEN * D_MODEL;   // 4096 x 3072
    unsigned short* woT   = qkv + (long)BATCH * S_LEN * QKV_N;    // 2048 x 2048
    unsigned short* wqkvT = woT + (long)D_MODEL * D_MODEL;        // 3072 x 2048
    unsigned short* Vt    = wqkvT;                                // reuses wqkvT

    const int M = BATCH * S_LEN;  // 4096
    const long xn = (long)M * D_MODEL;

    cast_f32_bf16<<<(int)(xn / 4 / 256), 256, 0, stream>>>(x, xb, xn);

    wtrans<<<dim3(D_MODEL / 32, D_MODEL / 32), 256, 0, stream>>>(wq, wqkvT, D_MODEL, D_MODEL);
    wtrans<<<dim3(KV_D / 32, D_MODEL / 32), 256, 0, stream>>>(wk, wqkvT + (long)D_MODEL * D_MODEL, D_MODEL, KV_D);
    wtrans<<<dim3(KV_D / 32, D_MODEL / 32), 256, 0, stream>>>(wv, wqkvT + (long)(D_MODEL + KV_D) * D_MODEL, D_MODEL, KV_D);
    wtrans<<<dim3(D_MODEL / 32, D_MODEL / 32), 256, 0, stream>>>(wo, woT, D_MODEL, D_MODEL);

    // QKV projection: 128x128 swizzled tiles (768 blocks = 3/CU)
    gemm_sw<128, false><<<dim3(M / 128, QKV_N / 128), 256, 0, stream>>>(
        xb, wqkvT, qkv, M, QKV_N, D_MODEL);

    rope2<<<M / 8, 256, 0, stream>>>(qkv);

    vtrans<<<dim3(S_LEN / 64, NKV, BATCH), 256, 0, stream>>>(qkv, Vt);

    flash7<<<dim3(8, NH, BATCH), 256, 0, stream>>>(qkv, Vt, Obuf);

    // out projection: 64x128 swizzled tiles (1024 blocks = 4/CU)
    gemm_sw<64, true><<<dim3(M / 64, D_MODEL / 128), 256, 0, stream>>>(
        Obuf, woT, out, M, D_MODEL, D_MODEL);
}